// Round 1
// baseline (718.092 us; speedup 1.0000x reference)
//
#include <hip/hip_runtime.h>

// ---------------------------------------------------------------------------
// RGAPConv decomposition:
//   per-node:  kA = x.(Wk@a1), qA = x.(Wq@a2), kG = x.(Wk@gnw_a), qG = x.(Wq@gnw_b)
//              Vm = x @ (Wv@msg_w) + (bv@msg_w + msg_b)
//   per-type:  relA[t] = rel_emb[t].a3 ; relM[t] = rel_emb[t]@msg_w
//   per-edge:  e = leaky_relu(kA[s]+qA[d]+relA[t]+cE) + sigmoid(rf.grw + kG[s]+qG[d]+cG) * b(rf)
//   segment softmax over dst (atomicMax / atomicAdd), scatter msg with f32 atomics.
// ---------------------------------------------------------------------------

__device__ __forceinline__ unsigned f2ord(float f) {
    unsigned u = __float_as_uint(f);
    return (u & 0x80000000u) ? ~u : (u | 0x80000000u);
}
__device__ __forceinline__ float ord2f(unsigned u) {
    return (u & 0x80000000u) ? __uint_as_float(u ^ 0x80000000u) : __uint_as_float(~u);
}

__device__ __forceinline__ float blk_reduce128(float v, float* red) {
    int t = threadIdx.x;
    red[t] = v;
    __syncthreads();
    for (int s = 64; s > 0; s >>= 1) {
        if (t < s) red[t] += red[t + s];
        __syncthreads();
    }
    float r = red[0];
    __syncthreads();
    return r;
}

// grid = 146 blocks x 128 threads. Builds all small tables.
__global__ void __launch_bounds__(128) precompute_kernel(
    const float* __restrict__ Wq, const float* __restrict__ bq,
    const float* __restrict__ Wk, const float* __restrict__ bk,
    const float* __restrict__ Wv, const float* __restrict__ bv,
    const float* __restrict__ rel_emb, const float* __restrict__ attn_vec,
    const float* __restrict__ msg_w, const float* __restrict__ msg_b,
    const float* __restrict__ gnw, const float* __restrict__ grb,
    const float* __restrict__ gnb,
    float* __restrict__ W2, float* __restrict__ c2,
    float* __restrict__ wkA, float* __restrict__ wqA,
    float* __restrict__ wkG, float* __restrict__ wqG,
    float* __restrict__ relA, float* __restrict__ relM,
    float* __restrict__ consts)
{
    __shared__ float red[128];
    int bid = blockIdx.x, j = threadIdx.x;
    if (bid < 128) {
        int i = bid;
        float acc = 0.f;
        #pragma unroll 8
        for (int k = 0; k < 128; ++k) acc = fmaf(Wv[i * 128 + k], msg_w[k * 128 + j], acc);
        W2[i * 128 + j] = acc;
        float r;
        r = blk_reduce128(Wk[i * 128 + j] * attn_vec[j], red);        if (j == 0) wkA[i] = r;
        r = blk_reduce128(Wq[i * 128 + j] * attn_vec[128 + j], red);  if (j == 0) wqA[i] = r;
        r = blk_reduce128(Wk[i * 128 + j] * gnw[j], red);             if (j == 0) wkG[i] = r;
        r = blk_reduce128(Wq[i * 128 + j] * gnw[128 + j], red);       if (j == 0) wqG[i] = r;
    } else if (bid < 144) {
        int t = bid - 128;
        float acc = 0.f;
        #pragma unroll 8
        for (int k = 0; k < 128; ++k) acc = fmaf(rel_emb[t * 128 + k], msg_w[k * 128 + j], acc);
        relM[t * 128 + j] = acc;
        float r = blk_reduce128(rel_emb[t * 128 + j] * attn_vec[256 + j], red);
        if (j == 0) relA[t] = r;
    } else if (bid == 144) {
        float acc = msg_b[j];
        #pragma unroll 8
        for (int k = 0; k < 128; ++k) acc = fmaf(bv[k], msg_w[k * 128 + j], acc);
        c2[j] = acc;
    } else {
        float r = blk_reduce128(bk[j] * attn_vec[j] + bq[j] * attn_vec[128 + j], red);
        if (j == 0) consts[0] = r;
        r = blk_reduce128(bk[j] * gnw[j] + bq[j] * gnw[128 + j], red);
        if (j == 0) consts[1] = r + grb[0] + gnb[0];
    }
}

// grid = n_nodes blocks x 128 threads: Vm row + 4 per-node scalars
__global__ void __launch_bounds__(128) node_kernel(
    const float* __restrict__ x, const float* __restrict__ W2,
    const float* __restrict__ c2,
    const float* __restrict__ wkA, const float* __restrict__ wqA,
    const float* __restrict__ wkG, const float* __restrict__ wqG,
    float* __restrict__ Vm, float* __restrict__ srcPack, float* __restrict__ dstPack)
{
    int n = blockIdx.x;
    int j = threadIdx.x;
    __shared__ float xs[128];
    xs[j] = x[n * 128 + j];
    __syncthreads();
    float acc = c2[j];
    #pragma unroll 8
    for (int k = 0; k < 128; ++k) acc = fmaf(xs[k], W2[k * 128 + j], acc);
    Vm[n * 128 + j] = acc;
    if (j < 4) {
        const float* w = (j == 0) ? wkA : (j == 1) ? wqA : (j == 2) ? wkG : wqG;
        float s = 0.f;
        #pragma unroll 8
        for (int k = 0; k < 128; ++k) s = fmaf(xs[k], w[k], s);
        if (j == 0)      srcPack[2 * n]     = s;  // kA
        else if (j == 1) dstPack[2 * n]     = s;  // qA
        else if (j == 2) srcPack[2 * n + 1] = s;  // kG
        else             dstPack[2 * n + 1] = s;  // qG
    }
}

__global__ void init_kernel(float* __restrict__ out, float* __restrict__ nodeSum,
                            unsigned* __restrict__ nodeMax, int out_n, int n_nodes)
{
    int i = blockIdx.x * blockDim.x + threadIdx.x;
    int stride = gridDim.x * blockDim.x;
    for (int idx = i; idx < out_n; idx += stride) out[idx] = 0.f;
    for (int idx = i; idx < n_nodes; idx += stride) {
        nodeSum[idx] = 0.f;
        nodeMax[idx] = 0x007FFFFFu;  // f2ord(-inf)
    }
}

// one thread per edge: e, gamma, b outputs + segment max
__global__ void __launch_bounds__(256) edge1_kernel(
    const int* __restrict__ ei, const int* __restrict__ et,
    const float4* __restrict__ erf,
    const float* __restrict__ rule_w1, const float* __restrict__ rule_b1,
    const float* __restrict__ rule_w2, const float* __restrict__ rule_b2,
    const float* __restrict__ grw,
    const float2* __restrict__ srcPack, const float2* __restrict__ dstPack,
    const float* __restrict__ relA, const float* __restrict__ consts,
    float* __restrict__ e_val, unsigned* __restrict__ nodeMax,
    float* __restrict__ gamma_out, float* __restrict__ b_out,
    int n_edges)
{
    __shared__ float s_rw1[512], s_rb1[128], s_rw2[128];
    int tid = threadIdx.x;
    for (int i = tid; i < 512; i += 256) s_rw1[i] = rule_w1[i];
    if (tid < 128) { s_rb1[tid] = rule_b1[tid]; s_rw2[tid] = rule_w2[tid]; }
    __syncthreads();
    int e = blockIdx.x * 256 + tid;
    if (e >= n_edges) return;

    int s = ei[e], d = ei[n_edges + e], t = et[e];
    float4 rf = erf[e];
    float2 ss = srcPack[s], dd = dstPack[d];

    float pre = ss.x + dd.x + relA[t] + consts[0];
    float e_base = pre >= 0.f ? pre : 0.2f * pre;

    float b = rule_b2[0];
    #pragma unroll 4
    for (int j = 0; j < 128; ++j) {
        float h = s_rb1[j];
        h = fmaf(rf.x, s_rw1[j], h);
        h = fmaf(rf.y, s_rw1[128 + j], h);
        h = fmaf(rf.z, s_rw1[256 + j], h);
        h = fmaf(rf.w, s_rw1[384 + j], h);
        h = fmaxf(h, 0.f);
        b = fmaf(h, s_rw2[j], b);
    }

    float gl = consts[1] + ss.y + dd.y;
    gl = fmaf(rf.x, grw[0], gl);
    gl = fmaf(rf.y, grw[1], gl);
    gl = fmaf(rf.z, grw[2], gl);
    gl = fmaf(rf.w, grw[3], gl);
    float gamma = 1.f / (1.f + __expf(-gl));

    float ev = e_base + gamma * b;
    gamma_out[e] = gamma;
    b_out[e] = b;
    e_val[e] = ev;
    atomicMax(&nodeMax[d], f2ord(ev));
}

// one thread per edge: exp(e - max) + segment sum
__global__ void __launch_bounds__(256) edge2_kernel(
    const int* __restrict__ ei, const unsigned* __restrict__ nodeMax,
    float* __restrict__ e_val, float* __restrict__ nodeSum, int n_edges)
{
    int e = blockIdx.x * blockDim.x + threadIdx.x;
    if (e >= n_edges) return;
    int d = ei[n_edges + e];
    float m = ord2f(nodeMax[d]);
    float ex = __expf(e_val[e] - m);
    e_val[e] = ex;
    atomicAdd(&nodeSum[d], ex);
}

// one wave (64 lanes) per edge: alpha + message scatter (2 cols per lane)
__global__ void __launch_bounds__(256) edge3_kernel(
    const int* __restrict__ ei, const int* __restrict__ et,
    const float* __restrict__ e_val, const float* __restrict__ nodeSum,
    const float* __restrict__ Vm, const float* __restrict__ relM,
    float* __restrict__ out, float* __restrict__ alpha_out, int n_edges)
{
    int lane = threadIdx.x & 63;
    int e = (blockIdx.x * 256 + threadIdx.x) >> 6;
    if (e >= n_edges) return;
    int s = ei[e], d = ei[n_edges + e], t = et[e];
    float ex = e_val[e];
    float alpha = ex / (nodeSum[d] + 1e-16f);
    if (lane == 0) alpha_out[e] = alpha;
    float v0 = Vm[s * 128 + lane]      + relM[t * 128 + lane];
    float v1 = Vm[s * 128 + 64 + lane] + relM[t * 128 + 64 + lane];
    atomicAdd(&out[d * 128 + lane],      v0 * alpha);
    atomicAdd(&out[d * 128 + 64 + lane], v1 * alpha);
}

extern "C" void kernel_launch(void* const* d_in, const int* in_sizes, int n_in,
                              void* d_out, int out_size, void* d_ws, size_t ws_size,
                              hipStream_t stream)
{
    const float* x        = (const float*)d_in[0];
    const int*   ei       = (const int*)d_in[1];
    const int*   et       = (const int*)d_in[2];
    const float* erf      = (const float*)d_in[3];
    const float* Wq       = (const float*)d_in[5];
    const float* bq       = (const float*)d_in[6];
    const float* Wk       = (const float*)d_in[7];
    const float* bk       = (const float*)d_in[8];
    const float* Wv       = (const float*)d_in[9];
    const float* bv       = (const float*)d_in[10];
    const float* rel_emb  = (const float*)d_in[11];
    const float* attn_vec = (const float*)d_in[12];
    const float* rule_w1  = (const float*)d_in[13];
    const float* rule_b1  = (const float*)d_in[14];
    const float* rule_w2  = (const float*)d_in[15];
    const float* rule_b2  = (const float*)d_in[16];
    const float* grw      = (const float*)d_in[17];
    const float* grb      = (const float*)d_in[18];
    const float* gnw      = (const float*)d_in[19];
    const float* gnb      = (const float*)d_in[20];
    const float* msg_w    = (const float*)d_in[21];
    const float* msg_b    = (const float*)d_in[22];

    const int n_nodes = in_sizes[0] / 128;
    const int n_edges = in_sizes[2];

    float* ws = (float*)d_ws;
    size_t off = 0;
    float* Vm      = ws + off; off += (size_t)n_nodes * 128;
    float* e_val   = ws + off; off += n_edges;
    float* srcPack = ws + off; off += 2 * (size_t)n_nodes;
    float* dstPack = ws + off; off += 2 * (size_t)n_nodes;
    unsigned* nodeMax = (unsigned*)(ws + off); off += n_nodes;
    float* nodeSum = ws + off; off += n_nodes;
    float* W2      = ws + off; off += 128 * 128;
    float* c2      = ws + off; off += 128;
    float* wkA     = ws + off; off += 128;
    float* wqA     = ws + off; off += 128;
    float* wkG     = ws + off; off += 128;
    float* wqG     = ws + off; off += 128;
    float* relA    = ws + off; off += 16;
    float* relM    = ws + off; off += 16 * 128;
    float* consts  = ws + off; off += 2;

    float* out       = (float*)d_out;
    float* alpha_out = out + (size_t)n_nodes * 128;
    float* gamma_out = alpha_out + n_edges;
    float* b_out     = gamma_out + n_edges;

    hipLaunchKernelGGL(precompute_kernel, dim3(146), dim3(128), 0, stream,
                       Wq, bq, Wk, bk, Wv, bv, rel_emb, attn_vec, msg_w, msg_b,
                       gnw, grb, gnb, W2, c2, wkA, wqA, wkG, wqG, relA, relM, consts);

    hipLaunchKernelGGL(node_kernel, dim3(n_nodes), dim3(128), 0, stream,
                       x, W2, c2, wkA, wqA, wkG, wqG, Vm, srcPack, dstPack);

    hipLaunchKernelGGL(init_kernel, dim3(512), dim3(256), 0, stream,
                       out, nodeSum, nodeMax, n_nodes * 128, n_nodes);

    hipLaunchKernelGGL(edge1_kernel, dim3((n_edges + 255) / 256), dim3(256), 0, stream,
                       ei, et, (const float4*)erf, rule_w1, rule_b1, rule_w2, rule_b2,
                       grw, (const float2*)srcPack, (const float2*)dstPack,
                       relA, consts, e_val, nodeMax, gamma_out, b_out, n_edges);

    hipLaunchKernelGGL(edge2_kernel, dim3((n_edges + 255) / 256), dim3(256), 0, stream,
                       ei, nodeMax, e_val, nodeSum, n_edges);

    hipLaunchKernelGGL(edge3_kernel, dim3((n_edges + 3) / 4), dim3(256), 0, stream,
                       ei, et, e_val, nodeSum, Vm, relM, out, alpha_out, n_edges);
}

// Round 2
// 493.493 us; speedup vs baseline: 1.4551x; 1.4551x over previous
//
#include <hip/hip_runtime.h>
#include <math.h>

// ---------------------------------------------------------------------------
// RGAPConv, CSR-gather formulation:
//   per-node:  kA,qA,kG,qG scalars + Vm = x @ (Wv@msg_w) + (bv@msg_w + msg_b)
//   per-edge:  e = leaky_relu(kA[s]+qA[d]+relA[t]+cE) + sigmoid(...) * b(rf)
//              (+ histogram deg[dst]++)
//   CSR build: block scan of deg -> rowPtr; scatter edge ids by dst
//   gather:    one wave per dst node: shuffle-reduce max/sum, alpha, register
//              accumulate messages, single coalesced store. NO f32 atomics.
// ---------------------------------------------------------------------------

__device__ __forceinline__ float wave_max(float v) {
    #pragma unroll
    for (int o = 32; o > 0; o >>= 1) v = fmaxf(v, __shfl_xor(v, o, 64));
    return v;
}
__device__ __forceinline__ float wave_sum(float v) {
    #pragma unroll
    for (int o = 32; o > 0; o >>= 1) v += __shfl_xor(v, o, 64);
    return v;
}

// grid = 146 blocks x 128 threads. Builds all small tables.
__global__ void __launch_bounds__(128) precompute_kernel(
    const float* __restrict__ Wq, const float* __restrict__ bq,
    const float* __restrict__ Wk, const float* __restrict__ bk,
    const float* __restrict__ Wv, const float* __restrict__ bv,
    const float* __restrict__ rel_emb, const float* __restrict__ attn_vec,
    const float* __restrict__ msg_w, const float* __restrict__ msg_b,
    const float* __restrict__ gnw, const float* __restrict__ grb,
    const float* __restrict__ gnb,
    const float* __restrict__ rule_w1, const float* __restrict__ rule_b1,
    const float* __restrict__ rule_w2,
    float* __restrict__ W2, float* __restrict__ c2,
    float* __restrict__ wkA, float* __restrict__ wqA,
    float* __restrict__ wkG, float* __restrict__ wqG,
    float* __restrict__ relA, float* __restrict__ relM,
    float* __restrict__ consts,
    float4* __restrict__ w1t, float2* __restrict__ w12)
{
    __shared__ float red[128];
    int bid = blockIdx.x, j = threadIdx.x;

    auto blk_reduce = [&](float v) -> float {
        red[j] = v;
        __syncthreads();
        for (int s = 64; s > 0; s >>= 1) {
            if (j < s) red[j] += red[j + s];
            __syncthreads();
        }
        float r = red[0];
        __syncthreads();
        return r;
    };

    if (bid < 128) {
        int i = bid;
        float acc = 0.f;
        #pragma unroll 8
        for (int k = 0; k < 128; ++k) acc = fmaf(Wv[i * 128 + k], msg_w[k * 128 + j], acc);
        W2[i * 128 + j] = acc;
        float r;
        r = blk_reduce(Wk[i * 128 + j] * attn_vec[j]);        if (j == 0) wkA[i] = r;
        r = blk_reduce(Wq[i * 128 + j] * attn_vec[128 + j]);  if (j == 0) wqA[i] = r;
        r = blk_reduce(Wk[i * 128 + j] * gnw[j]);             if (j == 0) wkG[i] = r;
        r = blk_reduce(Wq[i * 128 + j] * gnw[128 + j]);       if (j == 0) wqG[i] = r;
    } else if (bid < 144) {
        int t = bid - 128;
        float acc = 0.f;
        #pragma unroll 8
        for (int k = 0; k < 128; ++k) acc = fmaf(rel_emb[t * 128 + k], msg_w[k * 128 + j], acc);
        relM[t * 128 + j] = acc;
        float r = blk_reduce(rel_emb[t * 128 + j] * attn_vec[256 + j]);
        if (j == 0) relA[t] = r;
    } else if (bid == 144) {
        float acc = msg_b[j];
        #pragma unroll 8
        for (int k = 0; k < 128; ++k) acc = fmaf(bv[k], msg_w[k * 128 + j], acc);
        c2[j] = acc;
        w1t[j] = make_float4(rule_w1[j], rule_w1[128 + j], rule_w1[256 + j], rule_w1[384 + j]);
        w12[j] = make_float2(rule_b1[j], rule_w2[j]);
    } else {
        float r = blk_reduce(bk[j] * attn_vec[j] + bq[j] * attn_vec[128 + j]);
        if (j == 0) consts[0] = r;
        r = blk_reduce(bk[j] * gnw[j] + bq[j] * gnw[128 + j]);
        if (j == 0) consts[1] = r + grb[0] + gnb[0];
    }
}

// grid = n_nodes blocks x 128 threads: Vm row + 4 per-node scalars
__global__ void __launch_bounds__(128) node_kernel(
    const float* __restrict__ x, const float* __restrict__ W2,
    const float* __restrict__ c2,
    const float* __restrict__ wkA, const float* __restrict__ wqA,
    const float* __restrict__ wkG, const float* __restrict__ wqG,
    float* __restrict__ Vm, float* __restrict__ srcPack, float* __restrict__ dstPack)
{
    int n = blockIdx.x;
    int j = threadIdx.x;
    __shared__ float xs[128];
    xs[j] = x[n * 128 + j];
    __syncthreads();
    float acc = c2[j];
    #pragma unroll 8
    for (int k = 0; k < 128; ++k) acc = fmaf(xs[k], W2[k * 128 + j], acc);
    Vm[n * 128 + j] = acc;
    if (j < 4) {
        const float* w = (j == 0) ? wkA : (j == 1) ? wqA : (j == 2) ? wkG : wqG;
        float s = 0.f;
        #pragma unroll 8
        for (int k = 0; k < 128; ++k) s = fmaf(xs[k], w[k], s);
        if (j == 0)      srcPack[2 * n]     = s;  // kA
        else if (j == 1) dstPack[2 * n]     = s;  // qA
        else if (j == 2) srcPack[2 * n + 1] = s;  // kG
        else             dstPack[2 * n + 1] = s;  // qG
    }
}

__global__ void zero_kernel(int* __restrict__ deg, int n_nodes)
{
    int i = blockIdx.x * blockDim.x + threadIdx.x;
    if (i < n_nodes) deg[i] = 0;
}

// one thread per edge: e_val, gamma, b + deg histogram
__global__ void __launch_bounds__(256) edge1_kernel(
    const int* __restrict__ ei, const int* __restrict__ et,
    const float4* __restrict__ erf,
    const float4* __restrict__ w1t, const float2* __restrict__ w12,
    const float* __restrict__ rule_b2, const float* __restrict__ grw,
    const float2* __restrict__ srcPack, const float2* __restrict__ dstPack,
    const float* __restrict__ relA, const float* __restrict__ consts,
    float* __restrict__ e_val, float* __restrict__ gamma_out,
    float* __restrict__ b_out, int* __restrict__ deg,
    int n_edges)
{
    __shared__ float4 s_w1t[128];
    __shared__ float2 s_w12[128];
    int tid = threadIdx.x;
    if (tid < 128) { s_w1t[tid] = w1t[tid]; s_w12[tid] = w12[tid]; }
    __syncthreads();
    int e = blockIdx.x * 256 + tid;
    if (e >= n_edges) return;

    int s = ei[e], d = ei[n_edges + e], t = et[e];
    float4 rf = erf[e];
    float2 ss = srcPack[s], dd = dstPack[d];

    float pre = ss.x + dd.x + relA[t] + consts[0];
    float e_base = pre >= 0.f ? pre : 0.2f * pre;

    float b = rule_b2[0];
    #pragma unroll 8
    for (int j = 0; j < 128; ++j) {
        float4 w = s_w1t[j];
        float2 bw = s_w12[j];
        float h = fmaf(rf.x, w.x, fmaf(rf.y, w.y, fmaf(rf.z, w.z, fmaf(rf.w, w.w, bw.x))));
        b = fmaf(fmaxf(h, 0.f), bw.y, b);
    }

    float gl = fmaf(rf.x, grw[0], fmaf(rf.y, grw[1],
               fmaf(rf.z, grw[2], fmaf(rf.w, grw[3], consts[1] + ss.y + dd.y))));
    float gamma = 1.f / (1.f + __expf(-gl));

    gamma_out[e] = gamma;
    b_out[e] = b;
    e_val[e] = e_base + gamma * b;
    atomicAdd(&deg[d], 1);
}

// ---- CSR build: scan of deg -> rowPtr ----
// scan1: per-block (1024 elems) local exclusive scan + block totals
__global__ void __launch_bounds__(256) scan1_kernel(
    const int* __restrict__ deg, int* __restrict__ rowPtr,
    int* __restrict__ partials, int n)
{
    __shared__ int sdata[256];
    int tid = threadIdx.x;
    int base = blockIdx.x * 1024 + tid * 4;
    int v0 = (base + 0 < n) ? deg[base + 0] : 0;
    int v1 = (base + 1 < n) ? deg[base + 1] : 0;
    int v2 = (base + 2 < n) ? deg[base + 2] : 0;
    int v3 = (base + 3 < n) ? deg[base + 3] : 0;
    int tsum = v0 + v1 + v2 + v3;
    sdata[tid] = tsum;
    __syncthreads();
    #pragma unroll
    for (int off = 1; off < 256; off <<= 1) {
        int t = (tid >= off) ? sdata[tid - off] : 0;
        __syncthreads();
        sdata[tid] += t;
        __syncthreads();
    }
    int excl = sdata[tid] - tsum;  // exclusive prefix of this thread's chunk
    if (base + 0 < n) rowPtr[base + 0] = excl;
    if (base + 1 < n) rowPtr[base + 1] = excl + v0;
    if (base + 2 < n) rowPtr[base + 2] = excl + v0 + v1;
    if (base + 3 < n) rowPtr[base + 3] = excl + v0 + v1 + v2;
    if (tid == 255) partials[blockIdx.x] = sdata[255];
}

// scan2: single wave exclusive-scans the <=64 block partials
__global__ void __launch_bounds__(64) scan2_kernel(int* __restrict__ partials, int nb)
{
    int lane = threadIdx.x;
    int v = (lane < nb) ? partials[lane] : 0;
    int orig = v;
    #pragma unroll
    for (int off = 1; off < 64; off <<= 1) {
        int t = __shfl_up(v, off, 64);
        if (lane >= off) v += t;
    }
    if (lane < nb) partials[lane] = v - orig;
}

// scan3: add block offsets; write cursor copy (reuses deg array as cursor)
__global__ void __launch_bounds__(256) scan3_kernel(
    int* __restrict__ rowPtr, const int* __restrict__ partials,
    int* __restrict__ cursor, int n, int n_edges)
{
    int off = partials[blockIdx.x];
    int base = blockIdx.x * 1024 + threadIdx.x * 4;
    #pragma unroll
    for (int k = 0; k < 4; ++k) {
        int idx = base + k;
        if (idx < n) {
            int r = rowPtr[idx] + off;
            rowPtr[idx] = r;
            cursor[idx] = r;
        }
    }
    if (blockIdx.x == 0 && threadIdx.x == 0) rowPtr[n] = n_edges;
}

// scatter edge ids into CSR order
__global__ void __launch_bounds__(256) scatter_kernel(
    const int* __restrict__ ei, int* __restrict__ cursor,
    int* __restrict__ list, int n_edges)
{
    int e = blockIdx.x * blockDim.x + threadIdx.x;
    if (e >= n_edges) return;
    int d = ei[n_edges + e];
    int pos = atomicAdd(&cursor[d], 1);
    list[pos] = e;
}

// one wave per dst node: softmax over incoming edges + message accumulation
__global__ void __launch_bounds__(256) gather_kernel(
    const int* __restrict__ ei, const int* __restrict__ et,
    const int* __restrict__ rowPtr, const int* __restrict__ list,
    const float* __restrict__ e_val, const float* __restrict__ Vm,
    const float* __restrict__ relM,
    float* __restrict__ out, float* __restrict__ alpha_out,
    int n_nodes, int n_edges)
{
    int lane = threadIdx.x & 63;
    int d = blockIdx.x * 4 + (threadIdx.x >> 6);
    if (d >= n_nodes) return;
    int start = rowPtr[d];
    int deg = rowPtr[d + 1] - start;

    float acc0 = 0.f, acc1 = 0.f;
    if (deg > 0) {
        // pass 1: segment max
        float m = -INFINITY;
        for (int i = lane; i < deg; i += 64) m = fmaxf(m, e_val[list[start + i]]);
        m = wave_max(m);
        // pass 2: segment sum of exp
        float sum = 0.f;
        for (int i = lane; i < deg; i += 64) sum += __expf(e_val[list[start + i]] - m);
        sum = wave_sum(sum);
        float inv = 1.f / (sum + 1e-16f);
        // pass 3: alpha + accumulate, in chunks of 64 edges
        for (int c = 0; c < deg; c += 64) {
            int i = c + lane;
            float alpha = 0.f;
            int s = 0, t = 0;
            if (i < deg) {
                int e = list[start + i];
                alpha = __expf(e_val[e] - m) * inv;
                alpha_out[e] = alpha;
                s = ei[e];
                t = et[e];
            }
            int cnt = min(64, deg - c);
            for (int k = 0; k < cnt; ++k) {
                float a = __shfl(alpha, k, 64);
                int ss = __shfl(s, k, 64);
                int tt = __shfl(t, k, 64);
                acc0 = fmaf(a, Vm[ss * 128 + lane]      + relM[tt * 128 + lane],      acc0);
                acc1 = fmaf(a, Vm[ss * 128 + 64 + lane] + relM[tt * 128 + 64 + lane], acc1);
            }
        }
    }
    out[d * 128 + lane]      = acc0;
    out[d * 128 + 64 + lane] = acc1;
}

extern "C" void kernel_launch(void* const* d_in, const int* in_sizes, int n_in,
                              void* d_out, int out_size, void* d_ws, size_t ws_size,
                              hipStream_t stream)
{
    const float* x        = (const float*)d_in[0];
    const int*   ei       = (const int*)d_in[1];
    const int*   et       = (const int*)d_in[2];
    const float* erf      = (const float*)d_in[3];
    const float* Wq       = (const float*)d_in[5];
    const float* bq       = (const float*)d_in[6];
    const float* Wk       = (const float*)d_in[7];
    const float* bk       = (const float*)d_in[8];
    const float* Wv       = (const float*)d_in[9];
    const float* bv       = (const float*)d_in[10];
    const float* rel_emb  = (const float*)d_in[11];
    const float* attn_vec = (const float*)d_in[12];
    const float* rule_w1  = (const float*)d_in[13];
    const float* rule_b1  = (const float*)d_in[14];
    const float* rule_w2  = (const float*)d_in[15];
    const float* rule_b2  = (const float*)d_in[16];
    const float* grw      = (const float*)d_in[17];
    const float* grb      = (const float*)d_in[18];
    const float* gnw      = (const float*)d_in[19];
    const float* gnb      = (const float*)d_in[20];
    const float* msg_w    = (const float*)d_in[21];
    const float* msg_b    = (const float*)d_in[22];

    const int n_nodes = in_sizes[0] / 128;
    const int n_edges = in_sizes[2];
    const int nb = (n_nodes + 1023) / 1024;  // scan blocks (<= 64 required)

    float* ws = (float*)d_ws;
    size_t off = 0;
    float* Vm      = ws + off; off += (size_t)n_nodes * 128;
    float* e_val   = ws + off; off += n_edges;
    float* srcPack = ws + off; off += 2 * (size_t)n_nodes;
    float* dstPack = ws + off; off += 2 * (size_t)n_nodes;
    int*   deg     = (int*)(ws + off); off += n_nodes;        // reused as cursor
    int*   rowPtr  = (int*)(ws + off); off += n_nodes + 1;
    int*   list    = (int*)(ws + off); off += n_edges;
    int*   partials= (int*)(ws + off); off += 64;
    float* W2      = ws + off; off += 128 * 128;
    float* c2      = ws + off; off += 128;
    float* wkA     = ws + off; off += 128;
    float* wqA     = ws + off; off += 128;
    float* wkG     = ws + off; off += 128;
    float* wqG     = ws + off; off += 128;
    float* relA    = ws + off; off += 16;
    float* relM    = ws + off; off += 16 * 128;
    float* consts  = ws + off; off += 2;
    float4* w1t    = (float4*)(ws + off); off += 128 * 4;
    float2* w12    = (float2*)(ws + off); off += 128 * 2;

    float* out       = (float*)d_out;
    float* alpha_out = out + (size_t)n_nodes * 128;
    float* gamma_out = alpha_out + n_edges;
    float* b_out     = gamma_out + n_edges;

    hipLaunchKernelGGL(precompute_kernel, dim3(146), dim3(128), 0, stream,
                       Wq, bq, Wk, bk, Wv, bv, rel_emb, attn_vec, msg_w, msg_b,
                       gnw, grb, gnb, rule_w1, rule_b1, rule_w2,
                       W2, c2, wkA, wqA, wkG, wqG, relA, relM, consts, w1t, w12);

    hipLaunchKernelGGL(node_kernel, dim3(n_nodes), dim3(128), 0, stream,
                       x, W2, c2, wkA, wqA, wkG, wqG, Vm, srcPack, dstPack);

    hipLaunchKernelGGL(zero_kernel, dim3((n_nodes + 255) / 256), dim3(256), 0, stream,
                       deg, n_nodes);

    hipLaunchKernelGGL(edge1_kernel, dim3((n_edges + 255) / 256), dim3(256), 0, stream,
                       ei, et, (const float4*)erf, (const float4*)w1t, (const float2*)w12,
                       rule_b2, grw, (const float2*)srcPack, (const float2*)dstPack,
                       relA, consts, e_val, gamma_out, b_out, deg, n_edges);

    hipLaunchKernelGGL(scan1_kernel, dim3(nb), dim3(256), 0, stream,
                       deg, rowPtr, partials, n_nodes);
    hipLaunchKernelGGL(scan2_kernel, dim3(1), dim3(64), 0, stream,
                       partials, nb);
    hipLaunchKernelGGL(scan3_kernel, dim3(nb), dim3(256), 0, stream,
                       rowPtr, partials, deg /*cursor*/, n_nodes, n_edges);

    hipLaunchKernelGGL(scatter_kernel, dim3((n_edges + 255) / 256), dim3(256), 0, stream,
                       ei, deg /*cursor*/, list, n_edges);

    hipLaunchKernelGGL(gather_kernel, dim3((n_nodes + 3) / 4), dim3(256), 0, stream,
                       ei, et, rowPtr, list, e_val, Vm, relM, out, alpha_out,
                       n_nodes, n_edges);
}

// Round 3
// 383.068 us; speedup vs baseline: 1.8746x; 1.2883x over previous
//
#include <hip/hip_runtime.h>
#include <math.h>

// ---------------------------------------------------------------------------
// RGAPConv, CSR-gather formulation:
//   node:      tiled fp32 GEMM Vm = x @ (Wv@msg_w) + c2, 128x128 tile/block,
//              8x8 register tile/thread; scalar packs fused from LDS A-tile.
//   per-edge:  e = leaky_relu(kA[s]+qA[d]+relA[t]+cE) + sigmoid(...) * b(rf)
//   CSR build: histogram -> block scan -> scatter edge ids by dst
//   gather:    one wave per dst node, shuffle softmax, register accumulate.
// ---------------------------------------------------------------------------

__device__ __forceinline__ float wave_max(float v) {
    #pragma unroll
    for (int o = 32; o > 0; o >>= 1) v = fmaxf(v, __shfl_xor(v, o, 64));
    return v;
}
__device__ __forceinline__ float wave_sum(float v) {
    #pragma unroll
    for (int o = 32; o > 0; o >>= 1) v += __shfl_xor(v, o, 64);
    return v;
}

// grid = 146 blocks x 128 threads. Builds all small tables.
__global__ void __launch_bounds__(128) precompute_kernel(
    const float* __restrict__ Wq, const float* __restrict__ bq,
    const float* __restrict__ Wk, const float* __restrict__ bk,
    const float* __restrict__ Wv, const float* __restrict__ bv,
    const float* __restrict__ rel_emb, const float* __restrict__ attn_vec,
    const float* __restrict__ msg_w, const float* __restrict__ msg_b,
    const float* __restrict__ gnw, const float* __restrict__ grb,
    const float* __restrict__ gnb,
    const float* __restrict__ rule_w1, const float* __restrict__ rule_b1,
    const float* __restrict__ rule_w2,
    float* __restrict__ W2, float* __restrict__ c2,
    float* __restrict__ wkA, float* __restrict__ wqA,
    float* __restrict__ wkG, float* __restrict__ wqG,
    float* __restrict__ relA, float* __restrict__ relM,
    float* __restrict__ consts,
    float4* __restrict__ w1t, float2* __restrict__ w12)
{
    __shared__ float red[128];
    int bid = blockIdx.x, j = threadIdx.x;

    auto blk_reduce = [&](float v) -> float {
        red[j] = v;
        __syncthreads();
        for (int s = 64; s > 0; s >>= 1) {
            if (j < s) red[j] += red[j + s];
            __syncthreads();
        }
        float r = red[0];
        __syncthreads();
        return r;
    };

    if (bid < 128) {
        int i = bid;
        float acc = 0.f;
        #pragma unroll 8
        for (int k = 0; k < 128; ++k) acc = fmaf(Wv[i * 128 + k], msg_w[k * 128 + j], acc);
        W2[i * 128 + j] = acc;
        float r;
        r = blk_reduce(Wk[i * 128 + j] * attn_vec[j]);        if (j == 0) wkA[i] = r;
        r = blk_reduce(Wq[i * 128 + j] * attn_vec[128 + j]);  if (j == 0) wqA[i] = r;
        r = blk_reduce(Wk[i * 128 + j] * gnw[j]);             if (j == 0) wkG[i] = r;
        r = blk_reduce(Wq[i * 128 + j] * gnw[128 + j]);       if (j == 0) wqG[i] = r;
    } else if (bid < 144) {
        int t = bid - 128;
        float acc = 0.f;
        #pragma unroll 8
        for (int k = 0; k < 128; ++k) acc = fmaf(rel_emb[t * 128 + k], msg_w[k * 128 + j], acc);
        relM[t * 128 + j] = acc;
        float r = blk_reduce(rel_emb[t * 128 + j] * attn_vec[256 + j]);
        if (j == 0) relA[t] = r;
    } else if (bid == 144) {
        float acc = msg_b[j];
        #pragma unroll 8
        for (int k = 0; k < 128; ++k) acc = fmaf(bv[k], msg_w[k * 128 + j], acc);
        c2[j] = acc;
        w1t[j] = make_float4(rule_w1[j], rule_w1[128 + j], rule_w1[256 + j], rule_w1[384 + j]);
        w12[j] = make_float2(rule_b1[j], rule_w2[j]);
    } else {
        float r = blk_reduce(bk[j] * attn_vec[j] + bq[j] * attn_vec[128 + j]);
        if (j == 0) consts[0] = r;
        r = blk_reduce(bk[j] * gnw[j] + bq[j] * gnw[128 + j]);
        if (j == 0) consts[1] = r + grb[0] + gnb[0];
    }
}

// Tiled GEMM: 128 rows x 128 cols per block, K=128 resident.
// As stored transposed As[k][r] (LD=132): conflict-free b128 reads (lanes vary
// ty -> banks {0..31} exactly) and conflict-free staging writes (lanes vary r).
__global__ void __launch_bounds__(256) node_kernel(
    const float4* __restrict__ x4, const float4* __restrict__ W24,
    const float* __restrict__ c2,
    const float* __restrict__ wkA, const float* __restrict__ wqA,
    const float* __restrict__ wkG, const float* __restrict__ wqG,
    float* __restrict__ Vm, float2* __restrict__ srcPack, float2* __restrict__ dstPack,
    int n_nodes)
{
    __shared__ float As[128][132];
    __shared__ float Bs[128][128];
    const int tid = threadIdx.x;
    const int rowBase = blockIdx.x * 128;

    // stage B (full 128x128 W2): coalesced float4 read + float4 LDS write
    #pragma unroll
    for (int l = 0; l < 16; ++l) {
        int flat = l * 256 + tid;
        float4 w = W24[flat];
        *(float4*)&Bs[flat >> 5][(flat & 31) * 4] = w;
    }
    // stage A transposed: lanes vary r within an instruction -> conflict-free
    #pragma unroll
    for (int l = 0; l < 16; ++l) {
        int flat = l * 256 + tid;
        int r = flat & 127;
        int k4 = flat >> 7;
        int row = rowBase + r;
        float4 v = (row < n_nodes) ? x4[row * 32 + k4] : make_float4(0.f, 0.f, 0.f, 0.f);
        As[k4 * 4 + 0][r] = v.x;
        As[k4 * 4 + 1][r] = v.y;
        As[k4 * 4 + 2][r] = v.z;
        As[k4 * 4 + 3][r] = v.w;
    }
    __syncthreads();

    // fused per-node scalar packs: waves 0-1 -> (kA,kG), waves 2-3 -> (qA,qG)
    {
        int r = tid & 127, h = tid >> 7;
        const float* wa = h ? wqA : wkA;
        const float* wg = h ? wqG : wkG;
        float sA = 0.f, sG = 0.f;
        #pragma unroll 8
        for (int k = 0; k < 128; ++k) {
            float xv = As[k][r];
            sA = fmaf(xv, wa[k], sA);
            sG = fmaf(xv, wg[k], sG);
        }
        int row = rowBase + r;
        if (row < n_nodes) {
            if (h) dstPack[row] = make_float2(sA, sG);
            else   srcPack[row] = make_float2(sA, sG);
        }
    }

    const int tx = tid & 15, ty = tid >> 4;
    float acc[8][8];
    #pragma unroll
    for (int i = 0; i < 8; ++i)
        #pragma unroll
        for (int j = 0; j < 8; ++j) acc[i][j] = 0.f;

    #pragma unroll 2
    for (int k = 0; k < 128; ++k) {
        float4 a0 = *(const float4*)&As[k][ty * 8];
        float4 a1 = *(const float4*)&As[k][ty * 8 + 4];
        float4 b0 = *(const float4*)&Bs[k][tx * 8];
        float4 b1 = *(const float4*)&Bs[k][tx * 8 + 4];
        float a[8] = {a0.x, a0.y, a0.z, a0.w, a1.x, a1.y, a1.z, a1.w};
        float b[8] = {b0.x, b0.y, b0.z, b0.w, b1.x, b1.y, b1.z, b1.w};
        #pragma unroll
        for (int i = 0; i < 8; ++i)
            #pragma unroll
            for (int j = 0; j < 8; ++j)
                acc[i][j] = fmaf(a[i], b[j], acc[i][j]);
    }

    float c2v[8];
    #pragma unroll
    for (int j = 0; j < 8; ++j) c2v[j] = c2[tx * 8 + j];
    #pragma unroll
    for (int i = 0; i < 8; ++i) {
        int row = rowBase + ty * 8 + i;
        if (row < n_nodes) {
            float4 o0 = make_float4(acc[i][0] + c2v[0], acc[i][1] + c2v[1],
                                    acc[i][2] + c2v[2], acc[i][3] + c2v[3]);
            float4 o1 = make_float4(acc[i][4] + c2v[4], acc[i][5] + c2v[5],
                                    acc[i][6] + c2v[6], acc[i][7] + c2v[7]);
            *(float4*)&Vm[row * 128 + tx * 8]     = o0;
            *(float4*)&Vm[row * 128 + tx * 8 + 4] = o1;
        }
    }
}

__global__ void zero_kernel(int* __restrict__ deg, int n_nodes)
{
    int i = blockIdx.x * blockDim.x + threadIdx.x;
    if (i < n_nodes) deg[i] = 0;
}

// one thread per edge: e_val, gamma, b + deg histogram
__global__ void __launch_bounds__(256) edge1_kernel(
    const int* __restrict__ ei, const int* __restrict__ et,
    const float4* __restrict__ erf,
    const float4* __restrict__ w1t, const float2* __restrict__ w12,
    const float* __restrict__ rule_b2, const float* __restrict__ grw,
    const float2* __restrict__ srcPack, const float2* __restrict__ dstPack,
    const float* __restrict__ relA, const float* __restrict__ consts,
    float* __restrict__ e_val, float* __restrict__ gamma_out,
    float* __restrict__ b_out, int* __restrict__ deg,
    int n_edges)
{
    __shared__ float4 s_w1t[128];
    __shared__ float2 s_w12[128];
    int tid = threadIdx.x;
    if (tid < 128) { s_w1t[tid] = w1t[tid]; s_w12[tid] = w12[tid]; }
    __syncthreads();
    int e = blockIdx.x * 256 + tid;
    if (e >= n_edges) return;

    int s = ei[e], d = ei[n_edges + e], t = et[e];
    float4 rf = erf[e];
    float2 ss = srcPack[s], dd = dstPack[d];

    float pre = ss.x + dd.x + relA[t] + consts[0];
    float e_base = pre >= 0.f ? pre : 0.2f * pre;

    float b = rule_b2[0];
    #pragma unroll 8
    for (int j = 0; j < 128; ++j) {
        float4 w = s_w1t[j];
        float2 bw = s_w12[j];
        float h = fmaf(rf.x, w.x, fmaf(rf.y, w.y, fmaf(rf.z, w.z, fmaf(rf.w, w.w, bw.x))));
        b = fmaf(fmaxf(h, 0.f), bw.y, b);
    }

    float gl = fmaf(rf.x, grw[0], fmaf(rf.y, grw[1],
               fmaf(rf.z, grw[2], fmaf(rf.w, grw[3], consts[1] + ss.y + dd.y))));
    float gamma = 1.f / (1.f + __expf(-gl));

    gamma_out[e] = gamma;
    b_out[e] = b;
    e_val[e] = e_base + gamma * b;
    atomicAdd(&deg[d], 1);
}

// ---- CSR build: scan of deg -> rowPtr ----
__global__ void __launch_bounds__(256) scan1_kernel(
    const int* __restrict__ deg, int* __restrict__ rowPtr,
    int* __restrict__ partials, int n)
{
    __shared__ int sdata[256];
    int tid = threadIdx.x;
    int base = blockIdx.x * 1024 + tid * 4;
    int v0 = (base + 0 < n) ? deg[base + 0] : 0;
    int v1 = (base + 1 < n) ? deg[base + 1] : 0;
    int v2 = (base + 2 < n) ? deg[base + 2] : 0;
    int v3 = (base + 3 < n) ? deg[base + 3] : 0;
    int tsum = v0 + v1 + v2 + v3;
    sdata[tid] = tsum;
    __syncthreads();
    #pragma unroll
    for (int off = 1; off < 256; off <<= 1) {
        int t = (tid >= off) ? sdata[tid - off] : 0;
        __syncthreads();
        sdata[tid] += t;
        __syncthreads();
    }
    int excl = sdata[tid] - tsum;
    if (base + 0 < n) rowPtr[base + 0] = excl;
    if (base + 1 < n) rowPtr[base + 1] = excl + v0;
    if (base + 2 < n) rowPtr[base + 2] = excl + v0 + v1;
    if (base + 3 < n) rowPtr[base + 3] = excl + v0 + v1 + v2;
    if (tid == 255) partials[blockIdx.x] = sdata[255];
}

__global__ void __launch_bounds__(64) scan2_kernel(int* __restrict__ partials, int nb)
{
    int lane = threadIdx.x;
    int v = (lane < nb) ? partials[lane] : 0;
    int orig = v;
    #pragma unroll
    for (int off = 1; off < 64; off <<= 1) {
        int t = __shfl_up(v, off, 64);
        if (lane >= off) v += t;
    }
    if (lane < nb) partials[lane] = v - orig;
}

__global__ void __launch_bounds__(256) scan3_kernel(
    int* __restrict__ rowPtr, const int* __restrict__ partials,
    int* __restrict__ cursor, int n, int n_edges)
{
    int off = partials[blockIdx.x];
    int base = blockIdx.x * 1024 + threadIdx.x * 4;
    #pragma unroll
    for (int k = 0; k < 4; ++k) {
        int idx = base + k;
        if (idx < n) {
            int r = rowPtr[idx] + off;
            rowPtr[idx] = r;
            cursor[idx] = r;
        }
    }
    if (blockIdx.x == 0 && threadIdx.x == 0) rowPtr[n] = n_edges;
}

__global__ void __launch_bounds__(256) scatter_kernel(
    const int* __restrict__ ei, int* __restrict__ cursor,
    int* __restrict__ list, int n_edges)
{
    int e = blockIdx.x * blockDim.x + threadIdx.x;
    if (e >= n_edges) return;
    int d = ei[n_edges + e];
    int pos = atomicAdd(&cursor[d], 1);
    list[pos] = e;
}

// one wave per dst node: softmax over incoming edges + message accumulation
__global__ void __launch_bounds__(256) gather_kernel(
    const int* __restrict__ ei, const int* __restrict__ et,
    const int* __restrict__ rowPtr, const int* __restrict__ list,
    const float* __restrict__ e_val, const float* __restrict__ Vm,
    const float* __restrict__ relM,
    float* __restrict__ out, float* __restrict__ alpha_out,
    int n_nodes, int n_edges)
{
    int lane = threadIdx.x & 63;
    int d = blockIdx.x * 4 + (threadIdx.x >> 6);
    if (d >= n_nodes) return;
    int start = rowPtr[d];
    int deg = rowPtr[d + 1] - start;

    float acc0 = 0.f, acc1 = 0.f;
    if (deg > 0) {
        float m = -INFINITY;
        for (int i = lane; i < deg; i += 64) m = fmaxf(m, e_val[list[start + i]]);
        m = wave_max(m);
        float sum = 0.f;
        for (int i = lane; i < deg; i += 64) sum += __expf(e_val[list[start + i]] - m);
        sum = wave_sum(sum);
        float inv = 1.f / (sum + 1e-16f);
        for (int c = 0; c < deg; c += 64) {
            int i = c + lane;
            float alpha = 0.f;
            int s = 0, t = 0;
            if (i < deg) {
                int e = list[start + i];
                alpha = __expf(e_val[e] - m) * inv;
                alpha_out[e] = alpha;
                s = ei[e];
                t = et[e];
            }
            int cnt = min(64, deg - c);
            for (int k = 0; k < cnt; ++k) {
                float a = __shfl(alpha, k, 64);
                int ss = __shfl(s, k, 64);
                int tt = __shfl(t, k, 64);
                acc0 = fmaf(a, Vm[ss * 128 + lane]      + relM[tt * 128 + lane],      acc0);
                acc1 = fmaf(a, Vm[ss * 128 + 64 + lane] + relM[tt * 128 + 64 + lane], acc1);
            }
        }
    }
    out[d * 128 + lane]      = acc0;
    out[d * 128 + 64 + lane] = acc1;
}

extern "C" void kernel_launch(void* const* d_in, const int* in_sizes, int n_in,
                              void* d_out, int out_size, void* d_ws, size_t ws_size,
                              hipStream_t stream)
{
    const float* x        = (const float*)d_in[0];
    const int*   ei       = (const int*)d_in[1];
    const int*   et       = (const int*)d_in[2];
    const float* erf      = (const float*)d_in[3];
    const float* Wq       = (const float*)d_in[5];
    const float* bq       = (const float*)d_in[6];
    const float* Wk       = (const float*)d_in[7];
    const float* bk       = (const float*)d_in[8];
    const float* Wv       = (const float*)d_in[9];
    const float* bv       = (const float*)d_in[10];
    const float* rel_emb  = (const float*)d_in[11];
    const float* attn_vec = (const float*)d_in[12];
    const float* rule_w1  = (const float*)d_in[13];
    const float* rule_b1  = (const float*)d_in[14];
    const float* rule_w2  = (const float*)d_in[15];
    const float* rule_b2  = (const float*)d_in[16];
    const float* grw      = (const float*)d_in[17];
    const float* grb      = (const float*)d_in[18];
    const float* gnw      = (const float*)d_in[19];
    const float* gnb      = (const float*)d_in[20];
    const float* msg_w    = (const float*)d_in[21];
    const float* msg_b    = (const float*)d_in[22];

    const int n_nodes = in_sizes[0] / 128;
    const int n_edges = in_sizes[2];
    const int nb = (n_nodes + 1023) / 1024;  // scan blocks (<= 64 required)

    float* ws = (float*)d_ws;
    size_t off = 0;
    float* Vm      = ws + off; off += (size_t)n_nodes * 128;
    float* e_val   = ws + off; off += n_edges;
    float* srcPack = ws + off; off += 2 * (size_t)n_nodes;
    float* dstPack = ws + off; off += 2 * (size_t)n_nodes;
    int*   deg     = (int*)(ws + off); off += n_nodes;        // reused as cursor
    int*   rowPtr  = (int*)(ws + off); off += n_nodes + 4;    // padded for alignment
    int*   list    = (int*)(ws + off); off += n_edges;
    int*   partials= (int*)(ws + off); off += 64;
    float* W2      = ws + off; off += 128 * 128;
    float* c2      = ws + off; off += 128;
    float* wkA     = ws + off; off += 128;
    float* wqA     = ws + off; off += 128;
    float* wkG     = ws + off; off += 128;
    float* wqG     = ws + off; off += 128;
    float* relA    = ws + off; off += 16;
    float* relM    = ws + off; off += 16 * 128;
    float* consts  = ws + off; off += 2;
    off += 2;  // align to 4-float boundary for w1t
    float4* w1t    = (float4*)(ws + off); off += 128 * 4;
    float2* w12    = (float2*)(ws + off); off += 128 * 2;

    float* out       = (float*)d_out;
    float* alpha_out = out + (size_t)n_nodes * 128;
    float* gamma_out = alpha_out + n_edges;
    float* b_out     = gamma_out + n_edges;

    hipLaunchKernelGGL(precompute_kernel, dim3(146), dim3(128), 0, stream,
                       Wq, bq, Wk, bk, Wv, bv, rel_emb, attn_vec, msg_w, msg_b,
                       gnw, grb, gnb, rule_w1, rule_b1, rule_w2,
                       W2, c2, wkA, wqA, wkG, wqG, relA, relM, consts, w1t, w12);

    hipLaunchKernelGGL(node_kernel, dim3((n_nodes + 127) / 128), dim3(256), 0, stream,
                       (const float4*)x, (const float4*)W2, c2,
                       wkA, wqA, wkG, wqG, Vm, (float2*)srcPack, (float2*)dstPack,
                       n_nodes);

    hipLaunchKernelGGL(zero_kernel, dim3((n_nodes + 255) / 256), dim3(256), 0, stream,
                       deg, n_nodes);

    hipLaunchKernelGGL(edge1_kernel, dim3((n_edges + 255) / 256), dim3(256), 0, stream,
                       ei, et, (const float4*)erf, (const float4*)w1t, (const float2*)w12,
                       rule_b2, grw, (const float2*)srcPack, (const float2*)dstPack,
                       relA, consts, e_val, gamma_out, b_out, deg, n_edges);

    hipLaunchKernelGGL(scan1_kernel, dim3(nb), dim3(256), 0, stream,
                       deg, rowPtr, partials, n_nodes);
    hipLaunchKernelGGL(scan2_kernel, dim3(1), dim3(64), 0, stream,
                       partials, nb);
    hipLaunchKernelGGL(scan3_kernel, dim3(nb), dim3(256), 0, stream,
                       rowPtr, partials, deg /*cursor*/, n_nodes, n_edges);

    hipLaunchKernelGGL(scatter_kernel, dim3((n_edges + 255) / 256), dim3(256), 0, stream,
                       ei, deg /*cursor*/, list, n_edges);

    hipLaunchKernelGGL(gather_kernel, dim3((n_nodes + 3) / 4), dim3(256), 0, stream,
                       ei, et, rowPtr, list, e_val, Vm, relM, out, alpha_out,
                       n_nodes, n_edges);
}

// Round 4
// 349.784 us; speedup vs baseline: 2.0530x; 1.0952x over previous
//
#include <hip/hip_runtime.h>
#include <math.h>

// ---------------------------------------------------------------------------
// RGAPConv, CSR-gather formulation (R4):
//   node:      tiled fp32 GEMM -> Vm stored as packed bf16 (2/uint); fused
//              per-node scalar packs (fp32) + deg zeroing.
//   edge1:     e_val/gamma/b + dst histogram.
//   CSR build: scan -> scatter writes 8B payload {e_val, src|type<<27} in CSR
//              order, so gather reads are 100% coalesced.
//   gather:    one wave per dst node: shuffle softmax, bf16 Vm rows (256B),
//              writes out + per-node {m, inv}.  alpha written by a separate
//              fully-coalesced edge kernel (no random scatter).
// ---------------------------------------------------------------------------

__device__ __forceinline__ float wave_max(float v) {
    #pragma unroll
    for (int o = 32; o > 0; o >>= 1) v = fmaxf(v, __shfl_xor(v, o, 64));
    return v;
}
__device__ __forceinline__ float wave_sum(float v) {
    #pragma unroll
    for (int o = 32; o > 0; o >>= 1) v += __shfl_xor(v, o, 64);
    return v;
}

__device__ __forceinline__ unsigned bf16rne(float f) {
    unsigned u = __float_as_uint(f);
    return (u + 0x7FFFu + ((u >> 16) & 1u)) >> 16;  // round-to-nearest-even
}

// grid = 146 blocks x 128 threads. Builds all small tables.
__global__ void __launch_bounds__(128) precompute_kernel(
    const float* __restrict__ Wq, const float* __restrict__ bq,
    const float* __restrict__ Wk, const float* __restrict__ bk,
    const float* __restrict__ Wv, const float* __restrict__ bv,
    const float* __restrict__ rel_emb, const float* __restrict__ attn_vec,
    const float* __restrict__ msg_w, const float* __restrict__ msg_b,
    const float* __restrict__ gnw, const float* __restrict__ grb,
    const float* __restrict__ gnb,
    const float* __restrict__ rule_w1, const float* __restrict__ rule_b1,
    const float* __restrict__ rule_w2,
    float* __restrict__ W2, float* __restrict__ c2,
    float* __restrict__ wkA, float* __restrict__ wqA,
    float* __restrict__ wkG, float* __restrict__ wqG,
    float* __restrict__ relA, float* __restrict__ relM,
    float* __restrict__ consts,
    float4* __restrict__ w1t, float2* __restrict__ w12)
{
    __shared__ float red[128];
    int bid = blockIdx.x, j = threadIdx.x;

    auto blk_reduce = [&](float v) -> float {
        red[j] = v;
        __syncthreads();
        for (int s = 64; s > 0; s >>= 1) {
            if (j < s) red[j] += red[j + s];
            __syncthreads();
        }
        float r = red[0];
        __syncthreads();
        return r;
    };

    if (bid < 128) {
        int i = bid;
        float acc = 0.f;
        #pragma unroll 8
        for (int k = 0; k < 128; ++k) acc = fmaf(Wv[i * 128 + k], msg_w[k * 128 + j], acc);
        W2[i * 128 + j] = acc;
        float r;
        r = blk_reduce(Wk[i * 128 + j] * attn_vec[j]);        if (j == 0) wkA[i] = r;
        r = blk_reduce(Wq[i * 128 + j] * attn_vec[128 + j]);  if (j == 0) wqA[i] = r;
        r = blk_reduce(Wk[i * 128 + j] * gnw[j]);             if (j == 0) wkG[i] = r;
        r = blk_reduce(Wq[i * 128 + j] * gnw[128 + j]);       if (j == 0) wqG[i] = r;
    } else if (bid < 144) {
        int t = bid - 128;
        float acc = 0.f;
        #pragma unroll 8
        for (int k = 0; k < 128; ++k) acc = fmaf(rel_emb[t * 128 + k], msg_w[k * 128 + j], acc);
        relM[t * 128 + j] = acc;
        float r = blk_reduce(rel_emb[t * 128 + j] * attn_vec[256 + j]);
        if (j == 0) relA[t] = r;
    } else if (bid == 144) {
        float acc = msg_b[j];
        #pragma unroll 8
        for (int k = 0; k < 128; ++k) acc = fmaf(bv[k], msg_w[k * 128 + j], acc);
        c2[j] = acc;
        w1t[j] = make_float4(rule_w1[j], rule_w1[128 + j], rule_w1[256 + j], rule_w1[384 + j]);
        w12[j] = make_float2(rule_b1[j], rule_w2[j]);
    } else {
        float r = blk_reduce(bk[j] * attn_vec[j] + bq[j] * attn_vec[128 + j]);
        if (j == 0) consts[0] = r;
        r = blk_reduce(bk[j] * gnw[j] + bq[j] * gnw[128 + j]);
        if (j == 0) consts[1] = r + grb[0] + gnb[0];
    }
}

// Tiled GEMM: 128 rows x 128 cols per block, K=128 resident. Vm emitted as
// packed bf16 (uint = {col 2j (lo16), col 2j+1 (hi16)}). Also zeroes deg.
__global__ void __launch_bounds__(256) node_kernel(
    const float4* __restrict__ x4, const float4* __restrict__ W24,
    const float* __restrict__ c2,
    const float* __restrict__ wkA, const float* __restrict__ wqA,
    const float* __restrict__ wkG, const float* __restrict__ wqG,
    unsigned* __restrict__ Vmb, float2* __restrict__ srcPack,
    float2* __restrict__ dstPack, int* __restrict__ deg, int n_nodes)
{
    __shared__ float As[128][132];
    __shared__ float Bs[128][128];
    const int tid = threadIdx.x;
    const int rowBase = blockIdx.x * 128;

    if (tid < 128 && rowBase + tid < n_nodes) deg[rowBase + tid] = 0;

    #pragma unroll
    for (int l = 0; l < 16; ++l) {
        int flat = l * 256 + tid;
        float4 w = W24[flat];
        *(float4*)&Bs[flat >> 5][(flat & 31) * 4] = w;
    }
    #pragma unroll
    for (int l = 0; l < 16; ++l) {
        int flat = l * 256 + tid;
        int r = flat & 127;
        int k4 = flat >> 7;
        int row = rowBase + r;
        float4 v = (row < n_nodes) ? x4[row * 32 + k4] : make_float4(0.f, 0.f, 0.f, 0.f);
        As[k4 * 4 + 0][r] = v.x;
        As[k4 * 4 + 1][r] = v.y;
        As[k4 * 4 + 2][r] = v.z;
        As[k4 * 4 + 3][r] = v.w;
    }
    __syncthreads();

    // fused per-node scalar packs (fp32)
    {
        int r = tid & 127, h = tid >> 7;
        const float* wa = h ? wqA : wkA;
        const float* wg = h ? wqG : wkG;
        float sA = 0.f, sG = 0.f;
        #pragma unroll 8
        for (int k = 0; k < 128; ++k) {
            float xv = As[k][r];
            sA = fmaf(xv, wa[k], sA);
            sG = fmaf(xv, wg[k], sG);
        }
        int row = rowBase + r;
        if (row < n_nodes) {
            if (h) dstPack[row] = make_float2(sA, sG);
            else   srcPack[row] = make_float2(sA, sG);
        }
    }

    const int tx = tid & 15, ty = tid >> 4;
    float acc[8][8];
    #pragma unroll
    for (int i = 0; i < 8; ++i)
        #pragma unroll
        for (int j = 0; j < 8; ++j) acc[i][j] = 0.f;

    #pragma unroll 2
    for (int k = 0; k < 128; ++k) {
        float4 a0 = *(const float4*)&As[k][ty * 8];
        float4 a1 = *(const float4*)&As[k][ty * 8 + 4];
        float4 b0 = *(const float4*)&Bs[k][tx * 8];
        float4 b1 = *(const float4*)&Bs[k][tx * 8 + 4];
        float a[8] = {a0.x, a0.y, a0.z, a0.w, a1.x, a1.y, a1.z, a1.w};
        float b[8] = {b0.x, b0.y, b0.z, b0.w, b1.x, b1.y, b1.z, b1.w};
        #pragma unroll
        for (int i = 0; i < 8; ++i)
            #pragma unroll
            for (int j = 0; j < 8; ++j)
                acc[i][j] = fmaf(a[i], b[j], acc[i][j]);
    }

    float c2v[8];
    #pragma unroll
    for (int j = 0; j < 8; ++j) c2v[j] = c2[tx * 8 + j];
    #pragma unroll
    for (int i = 0; i < 8; ++i) {
        int row = rowBase + ty * 8 + i;
        if (row < n_nodes) {
            uint4 o;
            o.x = bf16rne(acc[i][0] + c2v[0]) | (bf16rne(acc[i][1] + c2v[1]) << 16);
            o.y = bf16rne(acc[i][2] + c2v[2]) | (bf16rne(acc[i][3] + c2v[3]) << 16);
            o.z = bf16rne(acc[i][4] + c2v[4]) | (bf16rne(acc[i][5] + c2v[5]) << 16);
            o.w = bf16rne(acc[i][6] + c2v[6]) | (bf16rne(acc[i][7] + c2v[7]) << 16);
            *(uint4*)&Vmb[row * 64 + tx * 4] = o;
        }
    }
}

// one thread per edge: e_val, gamma, b + deg histogram
__global__ void __launch_bounds__(256) edge1_kernel(
    const int* __restrict__ ei, const int* __restrict__ et,
    const float4* __restrict__ erf,
    const float4* __restrict__ w1t, const float2* __restrict__ w12,
    const float* __restrict__ rule_b2, const float* __restrict__ grw,
    const float2* __restrict__ srcPack, const float2* __restrict__ dstPack,
    const float* __restrict__ relA, const float* __restrict__ consts,
    float* __restrict__ e_val, float* __restrict__ gamma_out,
    float* __restrict__ b_out, int* __restrict__ deg,
    int n_edges)
{
    __shared__ float4 s_w1t[128];
    __shared__ float2 s_w12[128];
    int tid = threadIdx.x;
    if (tid < 128) { s_w1t[tid] = w1t[tid]; s_w12[tid] = w12[tid]; }
    __syncthreads();
    int e = blockIdx.x * 256 + tid;
    if (e >= n_edges) return;

    int s = ei[e], d = ei[n_edges + e], t = et[e];
    float4 rf = erf[e];
    float2 ss = srcPack[s], dd = dstPack[d];

    float pre = ss.x + dd.x + relA[t] + consts[0];
    float e_base = pre >= 0.f ? pre : 0.2f * pre;

    float b = rule_b2[0];
    #pragma unroll 8
    for (int j = 0; j < 128; ++j) {
        float4 w = s_w1t[j];
        float2 bw = s_w12[j];
        float h = fmaf(rf.x, w.x, fmaf(rf.y, w.y, fmaf(rf.z, w.z, fmaf(rf.w, w.w, bw.x))));
        b = fmaf(fmaxf(h, 0.f), bw.y, b);
    }

    float gl = fmaf(rf.x, grw[0], fmaf(rf.y, grw[1],
               fmaf(rf.z, grw[2], fmaf(rf.w, grw[3], consts[1] + ss.y + dd.y))));
    float gamma = 1.f / (1.f + __expf(-gl));

    gamma_out[e] = gamma;
    b_out[e] = b;
    e_val[e] = e_base + gamma * b;
    atomicAdd(&deg[d], 1);
}

// ---- CSR build: scan of deg -> rowPtr ----
__global__ void __launch_bounds__(256) scan1_kernel(
    const int* __restrict__ deg, int* __restrict__ rowPtr,
    int* __restrict__ partials, int n)
{
    __shared__ int sdata[256];
    int tid = threadIdx.x;
    int base = blockIdx.x * 1024 + tid * 4;
    int v0 = (base + 0 < n) ? deg[base + 0] : 0;
    int v1 = (base + 1 < n) ? deg[base + 1] : 0;
    int v2 = (base + 2 < n) ? deg[base + 2] : 0;
    int v3 = (base + 3 < n) ? deg[base + 3] : 0;
    int tsum = v0 + v1 + v2 + v3;
    sdata[tid] = tsum;
    __syncthreads();
    #pragma unroll
    for (int off = 1; off < 256; off <<= 1) {
        int t = (tid >= off) ? sdata[tid - off] : 0;
        __syncthreads();
        sdata[tid] += t;
        __syncthreads();
    }
    int excl = sdata[tid] - tsum;
    if (base + 0 < n) rowPtr[base + 0] = excl;
    if (base + 1 < n) rowPtr[base + 1] = excl + v0;
    if (base + 2 < n) rowPtr[base + 2] = excl + v0 + v1;
    if (base + 3 < n) rowPtr[base + 3] = excl + v0 + v1 + v2;
    if (tid == 255) partials[blockIdx.x] = sdata[255];
}

__global__ void __launch_bounds__(64) scan2_kernel(int* __restrict__ partials, int nb)
{
    int lane = threadIdx.x;
    int v = (lane < nb) ? partials[lane] : 0;
    int orig = v;
    #pragma unroll
    for (int off = 1; off < 64; off <<= 1) {
        int t = __shfl_up(v, off, 64);
        if (lane >= off) v += t;
    }
    if (lane < nb) partials[lane] = v - orig;
}

__global__ void __launch_bounds__(256) scan3_kernel(
    int* __restrict__ rowPtr, const int* __restrict__ partials,
    int* __restrict__ cursor, int n, int n_edges)
{
    int off = partials[blockIdx.x];
    int base = blockIdx.x * 1024 + threadIdx.x * 4;
    #pragma unroll
    for (int k = 0; k < 4; ++k) {
        int idx = base + k;
        if (idx < n) {
            int r = rowPtr[idx] + off;
            rowPtr[idx] = r;
            cursor[idx] = r;
        }
    }
    if (blockIdx.x == 0 && threadIdx.x == 0) rowPtr[n] = n_edges;
}

// scatter 8B payload {e_val, src | type<<27} into CSR order
__global__ void __launch_bounds__(256) scatter_kernel(
    const int* __restrict__ ei, const int* __restrict__ et,
    const float* __restrict__ e_val, int* __restrict__ cursor,
    float2* __restrict__ payload, int n_edges)
{
    int e = blockIdx.x * blockDim.x + threadIdx.x;
    if (e >= n_edges) return;
    int d = ei[n_edges + e];
    int pos = atomicAdd(&cursor[d], 1);
    int st = ei[e] | (et[e] << 27);
    payload[pos] = make_float2(e_val[e], __int_as_float(st));
}

// one wave per dst node: coalesced payload, shuffle softmax, bf16 Vm rows.
__global__ void __launch_bounds__(256) gather_kernel(
    const int* __restrict__ rowPtr, const float2* __restrict__ payload,
    const unsigned* __restrict__ Vmb, const float* __restrict__ relM,
    float* __restrict__ out, float2* __restrict__ nodeMS, int n_nodes)
{
    int lane = threadIdx.x & 63;
    int d = blockIdx.x * 4 + (threadIdx.x >> 6);
    if (d >= n_nodes) return;
    int start = rowPtr[d];
    int deg = rowPtr[d + 1] - start;

    float acc0 = 0.f, acc1 = 0.f;
    float m = -INFINITY, inv;

    if (deg <= 64) {
        float ev = -INFINITY;
        int st = 0;
        if (lane < deg) {
            float2 p = payload[start + lane];
            ev = p.x;
            st = __float_as_int(p.y);
        }
        m = wave_max(ev);
        float ex = (lane < deg) ? __expf(ev - m) : 0.f;
        float sum = wave_sum(ex);
        inv = 1.f / (sum + 1e-16f);
        float av = ex * inv;
        for (int k = 0; k < deg; ++k) {
            float a = __shfl(av, k, 64);
            int s_t = __shfl(st, k, 64);
            int ss = s_t & 0x7FFFFFF;
            int tt = ((unsigned)s_t) >> 27;
            unsigned v = Vmb[ss * 64 + lane];
            float2 rm = *(const float2*)&relM[tt * 128 + lane * 2];
            float f0 = __uint_as_float(v << 16);
            float f1 = __uint_as_float(v & 0xFFFF0000u);
            acc0 = fmaf(a, f0 + rm.x, acc0);
            acc1 = fmaf(a, f1 + rm.y, acc1);
        }
    } else {
        for (int i = lane; i < deg; i += 64) m = fmaxf(m, payload[start + i].x);
        m = wave_max(m);
        float sum = 0.f;
        for (int i = lane; i < deg; i += 64) sum += __expf(payload[start + i].x - m);
        sum = wave_sum(sum);
        inv = 1.f / (sum + 1e-16f);
        for (int c = 0; c < deg; c += 64) {
            int i = c + lane;
            float av = 0.f;
            int st = 0;
            if (i < deg) {
                float2 p = payload[start + i];
                av = __expf(p.x - m) * inv;
                st = __float_as_int(p.y);
            }
            int cnt = min(64, deg - c);
            for (int k = 0; k < cnt; ++k) {
                float a = __shfl(av, k, 64);
                int s_t = __shfl(st, k, 64);
                int ss = s_t & 0x7FFFFFF;
                int tt = ((unsigned)s_t) >> 27;
                unsigned v = Vmb[ss * 64 + lane];
                float2 rm = *(const float2*)&relM[tt * 128 + lane * 2];
                float f0 = __uint_as_float(v << 16);
                float f1 = __uint_as_float(v & 0xFFFF0000u);
                acc0 = fmaf(a, f0 + rm.x, acc0);
                acc1 = fmaf(a, f1 + rm.y, acc1);
            }
        }
    }
    if (lane == 0) nodeMS[d] = make_float2(m, inv);
    *(float2*)&out[d * 128 + lane * 2] = make_float2(acc0, acc1);
}

// fully-coalesced alpha: alpha[e] = exp(e_val[e] - m[d]) * inv[d]
__global__ void __launch_bounds__(256) alpha_kernel(
    const int* __restrict__ ei, const float* __restrict__ e_val,
    const float2* __restrict__ nodeMS, float* __restrict__ alpha_out, int n_edges)
{
    int e = blockIdx.x * blockDim.x + threadIdx.x;
    if (e >= n_edges) return;
    int d = ei[n_edges + e];
    float2 ms = nodeMS[d];
    alpha_out[e] = __expf(e_val[e] - ms.x) * ms.y;
}

extern "C" void kernel_launch(void* const* d_in, const int* in_sizes, int n_in,
                              void* d_out, int out_size, void* d_ws, size_t ws_size,
                              hipStream_t stream)
{
    const float* x        = (const float*)d_in[0];
    const int*   ei       = (const int*)d_in[1];
    const int*   et       = (const int*)d_in[2];
    const float* erf      = (const float*)d_in[3];
    const float* Wq       = (const float*)d_in[5];
    const float* bq       = (const float*)d_in[6];
    const float* Wk       = (const float*)d_in[7];
    const float* bk       = (const float*)d_in[8];
    const float* Wv       = (const float*)d_in[9];
    const float* bv       = (const float*)d_in[10];
    const float* rel_emb  = (const float*)d_in[11];
    const float* attn_vec = (const float*)d_in[12];
    const float* rule_w1  = (const float*)d_in[13];
    const float* rule_b1  = (const float*)d_in[14];
    const float* rule_w2  = (const float*)d_in[15];
    const float* rule_b2  = (const float*)d_in[16];
    const float* grw      = (const float*)d_in[17];
    const float* grb      = (const float*)d_in[18];
    const float* gnw      = (const float*)d_in[19];
    const float* gnb      = (const float*)d_in[20];
    const float* msg_w    = (const float*)d_in[21];
    const float* msg_b    = (const float*)d_in[22];

    const int n_nodes = in_sizes[0] / 128;
    const int n_edges = in_sizes[2];
    const int nb = (n_nodes + 1023) / 1024;  // scan blocks (<= 64 required)

    float* ws = (float*)d_ws;
    size_t off = 0;
    unsigned* Vmb  = (unsigned*)(ws + off); off += (size_t)n_nodes * 64;
    float* e_val   = ws + off; off += n_edges;
    float* srcPack = ws + off; off += 2 * (size_t)n_nodes;
    float* dstPack = ws + off; off += 2 * (size_t)n_nodes;
    int*   deg     = (int*)(ws + off); off += n_nodes;        // reused as cursor
    int*   rowPtr  = (int*)(ws + off); off += n_nodes + 4;
    float2* payload = (float2*)(ws + off); off += 2 * (size_t)n_edges;
    float2* nodeMS  = (float2*)(ws + off); off += 2 * (size_t)n_nodes;
    int*   partials= (int*)(ws + off); off += 64;
    float* W2      = ws + off; off += 128 * 128;
    float* c2      = ws + off; off += 128;
    float* wkA     = ws + off; off += 128;
    float* wqA     = ws + off; off += 128;
    float* wkG     = ws + off; off += 128;
    float* wqG     = ws + off; off += 128;
    float* relA    = ws + off; off += 16;
    float* relM    = ws + off; off += 16 * 128;
    float* consts  = ws + off; off += 2;
    off += 2;  // 16B alignment for w1t
    float4* w1t    = (float4*)(ws + off); off += 128 * 4;
    float2* w12    = (float2*)(ws + off); off += 128 * 2;

    float* out       = (float*)d_out;
    float* alpha_out = out + (size_t)n_nodes * 128;
    float* gamma_out = alpha_out + n_edges;
    float* b_out     = gamma_out + n_edges;

    hipLaunchKernelGGL(precompute_kernel, dim3(146), dim3(128), 0, stream,
                       Wq, bq, Wk, bk, Wv, bv, rel_emb, attn_vec, msg_w, msg_b,
                       gnw, grb, gnb, rule_w1, rule_b1, rule_w2,
                       W2, c2, wkA, wqA, wkG, wqG, relA, relM, consts, w1t, w12);

    hipLaunchKernelGGL(node_kernel, dim3((n_nodes + 127) / 128), dim3(256), 0, stream,
                       (const float4*)x, (const float4*)W2, c2,
                       wkA, wqA, wkG, wqG, Vmb, (float2*)srcPack, (float2*)dstPack,
                       deg, n_nodes);

    hipLaunchKernelGGL(edge1_kernel, dim3((n_edges + 255) / 256), dim3(256), 0, stream,
                       ei, et, (const float4*)erf, (const float4*)w1t, (const float2*)w12,
                       rule_b2, grw, (const float2*)srcPack, (const float2*)dstPack,
                       relA, consts, e_val, gamma_out, b_out, deg, n_edges);

    hipLaunchKernelGGL(scan1_kernel, dim3(nb), dim3(256), 0, stream,
                       deg, rowPtr, partials, n_nodes);
    hipLaunchKernelGGL(scan2_kernel, dim3(1), dim3(64), 0, stream,
                       partials, nb);
    hipLaunchKernelGGL(scan3_kernel, dim3(nb), dim3(256), 0, stream,
                       rowPtr, partials, deg /*cursor*/, n_nodes, n_edges);

    hipLaunchKernelGGL(scatter_kernel, dim3((n_edges + 255) / 256), dim3(256), 0, stream,
                       ei, et, e_val, deg /*cursor*/, payload, n_edges);

    hipLaunchKernelGGL(gather_kernel, dim3((n_nodes + 3) / 4), dim3(256), 0, stream,
                       rowPtr, payload, Vmb, relM, out, nodeMS, n_nodes);

    hipLaunchKernelGGL(alpha_kernel, dim3((n_edges + 255) / 256), dim3(256), 0, stream,
                       ei, e_val, nodeMS, alpha_out, n_edges);
}